// Round 1
// baseline (598.725 us; speedup 1.0000x reference)
//
#include <hip/hip_runtime.h>

// AbstractLinear: y = x @ W.T + b  (256x8192x8192, bf16 MFMA)
//                 low/high IBP bounds fused on the W staging path (fp32):
//                 P = W@(l+h), R = |W|@(h-l); low=.5(P-R)+b, high=.5(P+R)+b
#define M_TOTAL 256
#define N_TOTAL 8192
#define K_TOTAL 8192
#define TM 128
#define TN 64
#define BK 64
#define KITERS (K_TOTAL / BK)   // 128

typedef __attribute__((ext_vector_type(4))) float f32x4;
typedef __attribute__((ext_vector_type(8))) short s16x8;
typedef __attribute__((ext_vector_type(4))) int i32x4;

// pack two fp32 -> two bf16 (truncation) in one v_perm_b32
__device__ __forceinline__ int pk(float a, float b) {
    return (int)__builtin_amdgcn_perm(__float_as_uint(b), __float_as_uint(a), 0x07060302u);
}

__global__ __launch_bounds__(256, 1)
void abstract_linear_kernel(const float* __restrict__ x,
                            const float* __restrict__ low,
                            const float* __restrict__ high,
                            const float* __restrict__ W,
                            const float* __restrict__ bias,
                            float* __restrict__ out) {
    // XOR-swizzled bf16 tiles: element (row, k) lives at row*BK + ((k/8)^(row&7))*8 + k%8
    __shared__ __align__(16) unsigned short As[TM * BK];   // 16 KB
    __shared__ __align__(16) unsigned short Bs[TN * BK];   //  8 KB

    const int t  = threadIdx.x;
    const int bx = blockIdx.x;
    const int n0 = (bx & 127) * TN;     // bx and bx+128 share W tile AND XCD (bx%8 equal)
    const int m_tile = bx >> 7;
    const int m0 = m_tile * TM;
    const bool do_bounds = (m_tile == 0);

    // staging thread mapping
    const int ar  = t >> 1;             // A row 0..127 (x rows), 2 threads/row
    const int ach = t & 1;              // which 32-col half
    const int br  = t >> 2;             // B row 0..63 (W rows / outputs), 4 threads/row
    const int bq  = t & 3;              // 16-col quarter

    const float* xg = x + (size_t)(m0 + ar) * K_TOTAL + ach * 32;
    const float* wg = W + (size_t)(n0 + br) * K_TOTAL + bq * 16;
    const float* lg = low  + bq * 16;
    const float* hg = high + bq * 16;

    // wave / fragment mapping: 4 waves in 2x2, wave tile 64x32
    const int wave = t >> 6;
    const int lane = t & 63;
    const int wm  = wave >> 1;
    const int wn  = wave & 1;
    const int l15 = lane & 15;
    const int lq  = lane >> 4;          // 0..3

    f32x4 acc[4][2];
#pragma unroll
    for (int i = 0; i < 4; ++i)
#pragma unroll
        for (int j = 0; j < 2; ++j)
            acc[i][j] = (f32x4){0.f, 0.f, 0.f, 0.f};

    float P = 0.f, R = 0.f;

    f32x4 a_reg[8], w_reg[4], lo_reg[4], hi_reg[4];

    // prefetch K-tile 0
    {
        const f32x4* ap = (const f32x4*)xg;
#pragma unroll
        for (int j = 0; j < 8; ++j) a_reg[j] = ap[j];
        const f32x4* wp = (const f32x4*)wg;
#pragma unroll
        for (int j = 0; j < 4; ++j) w_reg[j] = wp[j];
        if (do_bounds) {
            const f32x4* lp = (const f32x4*)lg;
            const f32x4* hp = (const f32x4*)hg;
#pragma unroll
            for (int j = 0; j < 4; ++j) { lo_reg[j] = lp[j]; hi_reg[j] = hp[j]; }
        }
    }

    for (int it = 0; it < KITERS; ++it) {
        // convert current tile fp32 -> bf16 chunks (1 v_perm per 2 elems)
        i32x4 a_ch[4], b_ch[2];
#pragma unroll
        for (int j = 0; j < 4; ++j) {
            f32x4 u = a_reg[2*j], v = a_reg[2*j+1];
            a_ch[j][0] = pk(u[0], u[1]);
            a_ch[j][1] = pk(u[2], u[3]);
            a_ch[j][2] = pk(v[0], v[1]);
            a_ch[j][3] = pk(v[2], v[3]);
        }
#pragma unroll
        for (int j = 0; j < 2; ++j) {
            f32x4 u = w_reg[2*j], v = w_reg[2*j+1];
            b_ch[j][0] = pk(u[0], u[1]);
            b_ch[j][1] = pk(u[2], u[3]);
            b_ch[j][2] = pk(v[0], v[1]);
            b_ch[j][3] = pk(v[2], v[3]);
        }

        __syncthreads();   // previous tile's fragment reads done
#pragma unroll
        for (int j = 0; j < 4; ++j) {
            int cc  = ach * 4 + j;
            int pos = cc ^ (ar & 7);
            *(i32x4*)&As[ar * BK + pos * 8] = a_ch[j];
        }
#pragma unroll
        for (int j = 0; j < 2; ++j) {
            int cc  = bq * 2 + j;
            int pos = cc ^ (br & 7);
            *(i32x4*)&Bs[br * BK + pos * 8] = b_ch[j];
        }

        // fused IBP bounds accumulation (fp32, from the W values already in regs)
        if (do_bounds) {
#pragma unroll
            for (int j = 0; j < 4; ++j) {
                f32x4 w = w_reg[j], l = lo_reg[j], h = hi_reg[j];
#pragma unroll
                for (int e = 0; e < 4; ++e) {
                    float wv = w[e];
                    P = fmaf(wv,        l[e] + h[e], P);
                    R = fmaf(fabsf(wv), h[e] - l[e], R);
                }
            }
        }
        __syncthreads();   // LDS tile visible

        // prefetch next K-tile (overlaps with MFMA below)
        if (it + 1 < KITERS) {
            const int kb = (it + 1) * BK;
            const f32x4* ap = (const f32x4*)(xg + kb);
#pragma unroll
            for (int j = 0; j < 8; ++j) a_reg[j] = ap[j];
            const f32x4* wp = (const f32x4*)(wg + kb);
#pragma unroll
            for (int j = 0; j < 4; ++j) w_reg[j] = wp[j];
            if (do_bounds) {
                const f32x4* lp = (const f32x4*)(lg + kb);
                const f32x4* hp = (const f32x4*)(hg + kb);
#pragma unroll
                for (int j = 0; j < 4; ++j) { lo_reg[j] = lp[j]; hi_reg[j] = hp[j]; }
            }
        }

        // MFMA over the staged tile: 2 k-steps of 32
#pragma unroll
        for (int s = 0; s < 2; ++s) {
            s16x8 af[4], bf[2];
#pragma unroll
            for (int mi = 0; mi < 4; ++mi) {
                int row = wm * 64 + mi * 16 + l15;
                int pos = (s * 4 + lq) ^ (row & 7);
                af[mi] = *(const s16x8*)&As[row * BK + pos * 8];
            }
#pragma unroll
            for (int ni = 0; ni < 2; ++ni) {
                int row = wn * 32 + ni * 16 + l15;
                int pos = (s * 4 + lq) ^ (row & 7);
                bf[ni] = *(const s16x8*)&Bs[row * BK + pos * 8];
            }
#pragma unroll
            for (int mi = 0; mi < 4; ++mi)
#pragma unroll
                for (int ni = 0; ni < 2; ++ni)
                    acc[mi][ni] = __builtin_amdgcn_mfma_f32_16x16x32_bf16(
                        af[mi], bf[ni], acc[mi][ni], 0, 0, 0);
        }
    }

    // epilogue: y = acc + b   (C/D layout: col = lane&15, row = lq*4 + reg)
#pragma unroll
    for (int ni = 0; ni < 2; ++ni) {
        int go = n0 + wn * 32 + ni * 16 + l15;
        float bv = bias[go];
#pragma unroll
        for (int mi = 0; mi < 4; ++mi) {
            int gr = m0 + wm * 64 + mi * 16 + lq * 4;
#pragma unroll
            for (int r = 0; r < 4; ++r)
                out[(size_t)(gr + r) * N_TOTAL + go] = acc[mi][ni][r] + bv;
        }
    }

    // epilogue: bounds (quad reduction over the 4 threads of each W row)
    if (do_bounds) {
        P += __shfl_xor(P, 1);
        P += __shfl_xor(P, 2);
        R += __shfl_xor(R, 1);
        R += __shfl_xor(R, 2);
        if (bq == 0) {
            int o = n0 + br;
            float bv = bias[o];
            out[(size_t)M_TOTAL * N_TOTAL + o]           = 0.5f * (P - R) + bv;
            out[(size_t)M_TOTAL * N_TOTAL + N_TOTAL + o] = 0.5f * (P + R) + bv;
        }
    }
}

extern "C" void kernel_launch(void* const* d_in, const int* in_sizes, int n_in,
                              void* d_out, int out_size, void* d_ws, size_t ws_size,
                              hipStream_t stream) {
    const float* x    = (const float*)d_in[0];
    const float* low  = (const float*)d_in[1];
    const float* high = (const float*)d_in[2];
    const float* W    = (const float*)d_in[3];
    const float* b    = (const float*)d_in[4];
    float* out = (float*)d_out;

    dim3 grid(2 * (N_TOTAL / TN));   // 256 blocks: 2 M-tiles x 128 N-tiles
    dim3 block(256);
    hipLaunchKernelGGL(abstract_linear_kernel, grid, block, 0, stream,
                       x, low, high, W, b, out);
}

// Round 2
// 523.169 us; speedup vs baseline: 1.1444x; 1.1444x over previous
//
#include <hip/hip_runtime.h>

// AbstractLinear: y = x @ W.T + b  (256x8192x8192, bf16 MFMA)
//                 IBP bounds fused on W staging regs (fp32):
//                 P = W@(l+h), R = |W|@(h-l); low=.5(P-R)+b, high=.5(P+R)+b
// R2: software pipeline — 2-slot register prefetch (distance ~1 iter),
//     double-buffered bf16 LDS, ONE barrier/iter that waits lgkmcnt only
//     (inline asm) so global prefetch loads stay in flight across it.
#define M_TOTAL 256
#define N_TOTAL 8192
#define K_TOTAL 8192
#define TM 128
#define TN 64
#define BK 64
#define KITERS (K_TOTAL / BK)   // 128

typedef __attribute__((ext_vector_type(4))) float f32x4;
typedef __attribute__((ext_vector_type(8))) short s16x8;
typedef __attribute__((ext_vector_type(4))) int i32x4;

// pack two fp32 -> two bf16 (truncation) in one v_perm_b32
__device__ __forceinline__ int pk(float a, float b) {
    return (int)__builtin_amdgcn_perm(__float_as_uint(b), __float_as_uint(a), 0x07060302u);
}

// barrier with LDS-visibility only: does NOT drain vmcnt, so global
// prefetch loads issued before it remain in flight (compiler's
// __syncthreads would emit s_waitcnt vmcnt(0) and kill the pipeline).
__device__ __forceinline__ void barrier_lds() {
    asm volatile("s_waitcnt lgkmcnt(0)\n\ts_barrier" ::: "memory");
}

__global__ __launch_bounds__(256, 1)
void abstract_linear_kernel(const float* __restrict__ x,
                            const float* __restrict__ low,
                            const float* __restrict__ high,
                            const float* __restrict__ W,
                            const float* __restrict__ bias,
                            float* __restrict__ out) {
    // XOR-swizzled bf16 tiles: element (row,k) at row*BK + ((k/8)^(row&7))*8 + k%8
    __shared__ __align__(16) unsigned short As[2][TM * BK];   // 2 x 16 KB
    __shared__ __align__(16) unsigned short Bs[2][TN * BK];   // 2 x  8 KB

    const int t  = threadIdx.x;
    const int bx = blockIdx.x;
    const int n0 = (bx & 127) * TN;   // bx and bx+128 share W tile AND XCD (bx%8 equal)
    const int m_tile = bx >> 7;
    const int m0 = m_tile * TM;
    const bool do_bounds = (m_tile == 0);

    // staging thread mapping
    const int ar  = t >> 1;           // A row 0..127, 2 threads/row
    const int ach = t & 1;            // 32-col half
    const int br  = t >> 2;           // B row 0..63 (W rows), 4 threads/row
    const int bq  = t & 3;            // 16-col quarter

    const float* xg = x + (size_t)(m0 + ar) * K_TOTAL + ach * 32;
    const float* wg = W + (size_t)(n0 + br) * K_TOTAL + bq * 16;
    const float* lg = low  + bq * 16;
    const float* hg = high + bq * 16;

    // wave / fragment mapping: 4 waves 2x2, wave tile 64x32
    const int wave = t >> 6;
    const int lane = t & 63;
    const int wm  = wave >> 1;
    const int wn  = wave & 1;
    const int l15 = lane & 15;
    const int lq  = lane >> 4;

    f32x4 acc[4][2];
#pragma unroll
    for (int i = 0; i < 4; ++i)
#pragma unroll
        for (int j = 0; j < 2; ++j)
            acc[i][j] = (f32x4){0.f, 0.f, 0.f, 0.f};

    float P = 0.f, R = 0.f;

    // 2-slot register pipeline
    f32x4 a_reg[2][8], w_reg[2][4], lo_reg[2][4], hi_reg[2][4];

    auto issue = [&](int sl, int it) {
        const int kb = it * BK;
        const f32x4* ap = (const f32x4*)(xg + kb);
#pragma unroll
        for (int j = 0; j < 8; ++j) a_reg[sl][j] = ap[j];
        const f32x4* wp = (const f32x4*)(wg + kb);
#pragma unroll
        for (int j = 0; j < 4; ++j) w_reg[sl][j] = wp[j];
        if (do_bounds) {
            const f32x4* lp = (const f32x4*)(lg + kb);
            const f32x4* hp = (const f32x4*)(hg + kb);
#pragma unroll
            for (int j = 0; j < 4; ++j) { lo_reg[sl][j] = lp[j]; hi_reg[sl][j] = hp[j]; }
        }
    };

    auto convert_write = [&](int sl, int buf) {
        i32x4 a_ch[4], b_ch[2];
#pragma unroll
        for (int j = 0; j < 4; ++j) {
            f32x4 u = a_reg[sl][2*j], v = a_reg[sl][2*j+1];
            a_ch[j][0] = pk(u[0], u[1]);
            a_ch[j][1] = pk(u[2], u[3]);
            a_ch[j][2] = pk(v[0], v[1]);
            a_ch[j][3] = pk(v[2], v[3]);
        }
#pragma unroll
        for (int j = 0; j < 2; ++j) {
            f32x4 u = w_reg[sl][2*j], v = w_reg[sl][2*j+1];
            b_ch[j][0] = pk(u[0], u[1]);
            b_ch[j][1] = pk(u[2], u[3]);
            b_ch[j][2] = pk(v[0], v[1]);
            b_ch[j][3] = pk(v[2], v[3]);
        }
#pragma unroll
        for (int j = 0; j < 4; ++j) {
            int cc  = ach * 4 + j;
            int pos = cc ^ (ar & 7);
            *(i32x4*)&As[buf][ar * BK + pos * 8] = a_ch[j];
        }
#pragma unroll
        for (int j = 0; j < 2; ++j) {
            int cc  = bq * 2 + j;
            int pos = cc ^ (br & 7);
            *(i32x4*)&Bs[buf][br * BK + pos * 8] = b_ch[j];
        }
        if (do_bounds) {
#pragma unroll
            for (int j = 0; j < 4; ++j) {
                f32x4 w = w_reg[sl][j], l = lo_reg[sl][j], h = hi_reg[sl][j];
#pragma unroll
                for (int e = 0; e < 4; ++e) {
                    float wv = w[e];
                    P = fmaf(wv,        l[e] + h[e], P);
                    R = fmaf(fabsf(wv), h[e] - l[e], R);
                }
            }
        }
    };

    auto mfma_tile = [&](int buf) {
#pragma unroll
        for (int s = 0; s < 2; ++s) {
            s16x8 af[4], bf[2];
#pragma unroll
            for (int mi = 0; mi < 4; ++mi) {
                int row = wm * 64 + mi * 16 + l15;
                int pos = (s * 4 + lq) ^ (row & 7);
                af[mi] = *(const s16x8*)&As[buf][row * BK + pos * 8];
            }
#pragma unroll
            for (int ni = 0; ni < 2; ++ni) {
                int row = wn * 32 + ni * 16 + l15;
                int pos = (s * 4 + lq) ^ (row & 7);
                bf[ni] = *(const s16x8*)&Bs[buf][row * BK + pos * 8];
            }
#pragma unroll
            for (int mi = 0; mi < 4; ++mi)
#pragma unroll
                for (int ni = 0; ni < 2; ++ni)
                    acc[mi][ni] = __builtin_amdgcn_mfma_f32_16x16x32_bf16(
                        af[mi], bf[ni], acc[mi][ni], 0, 0, 0);
        }
    };

    // ---- prologue: tiles 0,1 in flight; tile 0 staged to LDS buf 0 ----
    issue(0, 0);
    issue(1, 1);
    convert_write(0, 0);
    barrier_lds();

    // ---- main pipeline, unrolled x2 so slot/buf indices are literals ----
    // iter i: issue(i+2) -> MFMA(tile i, buf i&1) -> convert+write(tile i+1,
    // buf (i+1)&1) -> lds-barrier.  vmcnt wait for tile i+1 sits after MFMA;
    // issue-to-wait distance ~1 full iteration.
    for (int it = 0; it < KITERS - 2; it += 2) {
        issue(0, it + 2);
        mfma_tile(0);
        convert_write(1, 1);
        barrier_lds();

        issue(1, it + 3);
        mfma_tile(1);
        convert_write(0, 0);
        barrier_lds();
    }
    // tail: it = 126, 127
    mfma_tile(0);
    convert_write(1, 1);
    barrier_lds();
    mfma_tile(1);

    // ---- epilogue: y = acc + b  (C/D layout: col = lane&15, row = lq*4+reg) ----
#pragma unroll
    for (int ni = 0; ni < 2; ++ni) {
        int go = n0 + wn * 32 + ni * 16 + l15;
        float bv = bias[go];
#pragma unroll
        for (int mi = 0; mi < 4; ++mi) {
            int gr = m0 + wm * 64 + mi * 16 + lq * 4;
#pragma unroll
            for (int r = 0; r < 4; ++r)
                out[(size_t)(gr + r) * N_TOTAL + go] = acc[mi][ni][r] + bv;
        }
    }

    // ---- epilogue: bounds (reduce over 4 threads per W row) ----
    if (do_bounds) {
        P += __shfl_xor(P, 1);
        P += __shfl_xor(P, 2);
        R += __shfl_xor(R, 1);
        R += __shfl_xor(R, 2);
        if (bq == 0) {
            int o = n0 + br;
            float bv = bias[o];
            out[(size_t)M_TOTAL * N_TOTAL + o]           = 0.5f * (P - R) + bv;
            out[(size_t)M_TOTAL * N_TOTAL + N_TOTAL + o] = 0.5f * (P + R) + bv;
        }
    }
}

extern "C" void kernel_launch(void* const* d_in, const int* in_sizes, int n_in,
                              void* d_out, int out_size, void* d_ws, size_t ws_size,
                              hipStream_t stream) {
    const float* x    = (const float*)d_in[0];
    const float* low  = (const float*)d_in[1];
    const float* high = (const float*)d_in[2];
    const float* W    = (const float*)d_in[3];
    const float* b    = (const float*)d_in[4];
    float* out = (float*)d_out;

    dim3 grid(2 * (N_TOTAL / TN));   // 256 blocks: 2 M-tiles x 128 N-tiles
    dim3 block(256);
    hipLaunchKernelGGL(abstract_linear_kernel, grid, block, 0, stream,
                       x, low, high, W, b, out);
}

// Round 3
// 472.712 us; speedup vs baseline: 1.2666x; 1.1067x over previous
//
#include <hip/hip_runtime.h>

// AbstractLinear: y = x @ W.T + b  (256x8192x8192, bf16 MFMA)
//                 IBP bounds fused on W staging regs (fp32):
//                 P = W@(l+h), R = |W|@(h-l); low=.5(P-R)+b, high=.5(P+R)+b
// R3: coalesced staging lane map — each wave load instruction touches 16
//     cache lines (4 tile rows x 256B), not 64. Thread t loads row j*16+(t>>4),
//     cols (t&15)*4. LDS writes become swizzled ds_write_b64 (16B-chunk XOR
//     layout unchanged -> MFMA read path identical to R2, verified).
//     Bounds: per-thread P[4]/R[4], shfl_xor-reduced over 16 lanes.
#define M_TOTAL 256
#define N_TOTAL 8192
#define K_TOTAL 8192
#define TM 128
#define TN 64
#define BK 64
#define KITERS (K_TOTAL / BK)   // 128

typedef __attribute__((ext_vector_type(4))) float f32x4;
typedef __attribute__((ext_vector_type(8))) short s16x8;
typedef __attribute__((ext_vector_type(2))) int i32x2;

// pack two fp32 -> two bf16 (truncation) in one v_perm_b32
__device__ __forceinline__ int pk(float a, float b) {
    return (int)__builtin_amdgcn_perm(__float_as_uint(b), __float_as_uint(a), 0x07060302u);
}

// barrier with LDS-visibility only: does NOT drain vmcnt, so global
// prefetch loads issued before it remain in flight.
__device__ __forceinline__ void barrier_lds() {
    asm volatile("s_waitcnt lgkmcnt(0)\n\ts_barrier" ::: "memory");
}

__global__ __launch_bounds__(256, 1)
void abstract_linear_kernel(const float* __restrict__ x,
                            const float* __restrict__ low,
                            const float* __restrict__ high,
                            const float* __restrict__ W,
                            const float* __restrict__ bias,
                            float* __restrict__ out) {
    // XOR-swizzled bf16 tiles: element (row,k) at row*BK + ((k/8)^(row&7))*8 + k%8
    __shared__ __align__(16) unsigned short As[2][TM * BK];   // 2 x 16 KB
    __shared__ __align__(16) unsigned short Bs[2][TN * BK];   // 2 x  8 KB

    const int t  = threadIdx.x;
    const int bx = blockIdx.x;
    const int n0 = (bx & 127) * TN;   // bx and bx+128 share W tile AND XCD (bx%8 equal)
    const int m_tile = bx >> 7;
    const int m0 = m_tile * TM;
    const bool do_bounds = (m_tile == 0);

    // coalesced staging map: thread t -> row j*16 + g, cols sg*4..sg*4+3
    const int g  = t >> 4;            // 0..15
    const int sg = t & 15;            // 0..15

    const float* xg = x + (size_t)(m0 + g) * K_TOTAL + sg * 4;
    const float* wg = W + (size_t)(n0 + g) * K_TOTAL + sg * 4;
    const float* lg = low  + sg * 4;
    const float* hg = high + sg * 4;

    // wave / fragment mapping: 4 waves 2x2, wave tile 64x32
    const int wave = t >> 6;
    const int lane = t & 63;
    const int wm  = wave >> 1;
    const int wn  = wave & 1;
    const int l15 = lane & 15;
    const int lq  = lane >> 4;

    f32x4 acc[4][2];
#pragma unroll
    for (int i = 0; i < 4; ++i)
#pragma unroll
        for (int j = 0; j < 2; ++j)
            acc[i][j] = (f32x4){0.f, 0.f, 0.f, 0.f};

    // bounds accumulators: P[j]/R[j] for W row j*16+g, this thread's 4 cols
    float P[4] = {0.f, 0.f, 0.f, 0.f};
    float R[4] = {0.f, 0.f, 0.f, 0.f};

    // 2-slot register pipeline
    f32x4 a_reg[2][8], w_reg[2][4], lo_reg[2], hi_reg[2];

    auto issue = [&](int sl, int it) {
        const int kb = it * BK;
#pragma unroll
        for (int j = 0; j < 8; ++j)
            a_reg[sl][j] = *(const f32x4*)(xg + (size_t)j * 16 * K_TOTAL + kb);
#pragma unroll
        for (int j = 0; j < 4; ++j)
            w_reg[sl][j] = *(const f32x4*)(wg + (size_t)j * 16 * K_TOTAL + kb);
        if (do_bounds) {
            lo_reg[sl] = *(const f32x4*)(lg + kb);
            hi_reg[sl] = *(const f32x4*)(hg + kb);
        }
    };

    const int a_chunk = sg >> 1;      // 16B chunk within row
    const int a_half  = sg & 1;       // 8B half within chunk

    auto convert_write = [&](int sl, int buf) {
#pragma unroll
        for (int j = 0; j < 8; ++j) {
            f32x4 u = a_reg[sl][j];
            i32x2 d;
            d[0] = pk(u[0], u[1]);
            d[1] = pk(u[2], u[3]);
            int row = j * 16 + g;
            int pos = a_chunk ^ (row & 7);
            *(i32x2*)&As[buf][row * BK + pos * 8 + a_half * 4] = d;
        }
#pragma unroll
        for (int j = 0; j < 4; ++j) {
            f32x4 u = w_reg[sl][j];
            i32x2 d;
            d[0] = pk(u[0], u[1]);
            d[1] = pk(u[2], u[3]);
            int row = j * 16 + g;
            int pos = a_chunk ^ (row & 7);
            *(i32x2*)&Bs[buf][row * BK + pos * 8 + a_half * 4] = d;
        }
        if (do_bounds) {
            f32x4 l = lo_reg[sl], h = hi_reg[sl];
#pragma unroll
            for (int j = 0; j < 4; ++j) {
                f32x4 w = w_reg[sl][j];
#pragma unroll
                for (int e = 0; e < 4; ++e) {
                    float wv = w[e];
                    P[j] = fmaf(wv,        l[e] + h[e], P[j]);
                    R[j] = fmaf(fabsf(wv), h[e] - l[e], R[j]);
                }
            }
        }
    };

    auto mfma_tile = [&](int buf) {
#pragma unroll
        for (int s = 0; s < 2; ++s) {
            s16x8 af[4], bf[2];
#pragma unroll
            for (int mi = 0; mi < 4; ++mi) {
                int row = wm * 64 + mi * 16 + l15;
                int pos = (s * 4 + lq) ^ (row & 7);
                af[mi] = *(const s16x8*)&As[buf][row * BK + pos * 8];
            }
#pragma unroll
            for (int ni = 0; ni < 2; ++ni) {
                int row = wn * 32 + ni * 16 + l15;
                int pos = (s * 4 + lq) ^ (row & 7);
                bf[ni] = *(const s16x8*)&Bs[buf][row * BK + pos * 8];
            }
#pragma unroll
            for (int mi = 0; mi < 4; ++mi)
#pragma unroll
                for (int ni = 0; ni < 2; ++ni)
                    acc[mi][ni] = __builtin_amdgcn_mfma_f32_16x16x32_bf16(
                        af[mi], bf[ni], acc[mi][ni], 0, 0, 0);
        }
    };

    // ---- prologue: tiles 0,1 in flight; tile 0 staged to LDS buf 0 ----
    issue(0, 0);
    issue(1, 1);
    convert_write(0, 0);
    barrier_lds();

    // ---- main pipeline, unrolled x2 (slot/buf indices literal) ----
    for (int it = 0; it < KITERS - 2; it += 2) {
        issue(0, it + 2);
        mfma_tile(0);
        convert_write(1, 1);
        barrier_lds();

        issue(1, it + 3);
        mfma_tile(1);
        convert_write(0, 0);
        barrier_lds();
    }
    // tail: tiles 126, 127
    mfma_tile(0);
    convert_write(1, 1);
    barrier_lds();
    mfma_tile(1);

    // ---- epilogue: y = acc + b  (C/D layout: col = lane&15, row = lq*4+reg) ----
#pragma unroll
    for (int ni = 0; ni < 2; ++ni) {
        int go = n0 + wn * 32 + ni * 16 + l15;
        float bv = bias[go];
#pragma unroll
        for (int mi = 0; mi < 4; ++mi) {
            int gr = m0 + wm * 64 + mi * 16 + lq * 4;
#pragma unroll
            for (int r = 0; r < 4; ++r)
                out[(size_t)(gr + r) * N_TOTAL + go] = acc[mi][ni][r] + bv;
        }
    }

    // ---- epilogue: bounds (reduce over the 16 lanes sharing t>>4) ----
    if (do_bounds) {
#pragma unroll
        for (int j = 0; j < 4; ++j) {
            float p = P[j], r = R[j];
            p += __shfl_xor(p, 1);
            p += __shfl_xor(p, 2);
            p += __shfl_xor(p, 4);
            p += __shfl_xor(p, 8);
            r += __shfl_xor(r, 1);
            r += __shfl_xor(r, 2);
            r += __shfl_xor(r, 4);
            r += __shfl_xor(r, 8);
            if (sg == 0) {
                int o = n0 + j * 16 + g;
                float bv = bias[o];
                out[(size_t)M_TOTAL * N_TOTAL + o]           = 0.5f * (p - r) + bv;
                out[(size_t)M_TOTAL * N_TOTAL + N_TOTAL + o] = 0.5f * (p + r) + bv;
            }
        }
    }
}

extern "C" void kernel_launch(void* const* d_in, const int* in_sizes, int n_in,
                              void* d_out, int out_size, void* d_ws, size_t ws_size,
                              hipStream_t stream) {
    const float* x    = (const float*)d_in[0];
    const float* low  = (const float*)d_in[1];
    const float* high = (const float*)d_in[2];
    const float* W    = (const float*)d_in[3];
    const float* b    = (const float*)d_in[4];
    float* out = (float*)d_out;

    dim3 grid(2 * (N_TOTAL / TN));   // 256 blocks: 2 M-tiles x 128 N-tiles
    dim3 block(256);
    hipLaunchKernelGGL(abstract_linear_kernel, grid, block, 0, stream,
                       x, low, high, W, b, out);
}

// Round 4
// 444.875 us; speedup vs baseline: 1.3458x; 1.0626x over previous
//
#include <hip/hip_runtime.h>

// AbstractLinear: y = x @ W.T + b  (256x8192x8192, bf16 MFMA)
//                 IBP bounds fused on W staging regs (fp32):
//                 P = W@(l+h), R = |W|@(h-l); low=.5(P-R)+b, high=.5(P+R)+b
// R4: occupancy 4->8 waves/CU. TM=64/TN=64, 512 blocks = 2 blocks/CU =
//     2 waves/SIMD so vmcnt/barrier stalls of one wave are covered by the
//     other (m114 co-scheduling). R3's verified swizzle / coalesced staging /
//     lgkmcnt-only barrier / 2-slot pipeline unchanged.
#define M_TOTAL 256
#define N_TOTAL 8192
#define K_TOTAL 8192
#define TM 64
#define TN 64
#define BK 64
#define KITERS (K_TOTAL / BK)   // 128

typedef __attribute__((ext_vector_type(4))) float f32x4;
typedef __attribute__((ext_vector_type(8))) short s16x8;
typedef __attribute__((ext_vector_type(2))) int i32x2;

// pack two fp32 -> two bf16 (truncation) in one v_perm_b32
__device__ __forceinline__ int pk(float a, float b) {
    return (int)__builtin_amdgcn_perm(__float_as_uint(b), __float_as_uint(a), 0x07060302u);
}

// barrier with LDS-visibility only: does NOT drain vmcnt, so global
// prefetch loads issued before it remain in flight.
__device__ __forceinline__ void barrier_lds() {
    asm volatile("s_waitcnt lgkmcnt(0)\n\ts_barrier" ::: "memory");
}

__global__ __launch_bounds__(256, 2)
void abstract_linear_kernel(const float* __restrict__ x,
                            const float* __restrict__ low,
                            const float* __restrict__ high,
                            const float* __restrict__ W,
                            const float* __restrict__ bias,
                            float* __restrict__ out) {
    // XOR-swizzled bf16 tiles: element (row,k) at row*BK + ((k/8)^(row&7))*8 + k%8
    __shared__ __align__(16) unsigned short As[2][TM * BK];   // 2 x 8 KB
    __shared__ __align__(16) unsigned short Bs[2][TN * BK];   // 2 x 8 KB

    const int t  = threadIdx.x;
    const int bx = blockIdx.x;
    const int n0 = (bx & 127) * TN;   // bx, bx+128, bx+256, bx+384 share W tile & XCD
    const int m_tile = bx >> 7;       // 0..3
    const int m0 = m_tile * TM;
    const bool do_bounds = (m_tile == 0);

    // coalesced staging map: thread t -> rows j*16 + g, cols sg*4..sg*4+3
    const int g  = t >> 4;            // 0..15
    const int sg = t & 15;            // 0..15

    const float* xg = x + (size_t)(m0 + g) * K_TOTAL + sg * 4;
    const float* wg = W + (size_t)(n0 + g) * K_TOTAL + sg * 4;
    const float* lg = low  + sg * 4;
    const float* hg = high + sg * 4;

    // wave / fragment mapping: 4 waves 2x2, wave tile 32x32
    const int wave = t >> 6;
    const int lane = t & 63;
    const int wm  = wave >> 1;
    const int wn  = wave & 1;
    const int l15 = lane & 15;
    const int lq  = lane >> 4;

    f32x4 acc[2][2];
#pragma unroll
    for (int i = 0; i < 2; ++i)
#pragma unroll
        for (int j = 0; j < 2; ++j)
            acc[i][j] = (f32x4){0.f, 0.f, 0.f, 0.f};

    // bounds accumulators: P[j]/R[j] for W row j*16+g, this thread's 4 cols
    float P[4] = {0.f, 0.f, 0.f, 0.f};
    float R[4] = {0.f, 0.f, 0.f, 0.f};

    // 2-slot register pipeline
    f32x4 a_reg[2][4], w_reg[2][4], lo_reg[2], hi_reg[2];

    auto issue = [&](int sl, int it) {
        const int kb = it * BK;
#pragma unroll
        for (int j = 0; j < 4; ++j)
            a_reg[sl][j] = *(const f32x4*)(xg + (size_t)j * 16 * K_TOTAL + kb);
#pragma unroll
        for (int j = 0; j < 4; ++j)
            w_reg[sl][j] = *(const f32x4*)(wg + (size_t)j * 16 * K_TOTAL + kb);
        if (do_bounds) {
            lo_reg[sl] = *(const f32x4*)(lg + kb);
            hi_reg[sl] = *(const f32x4*)(hg + kb);
        }
    };

    const int a_chunk = sg >> 1;      // 16B chunk within row
    const int a_half  = sg & 1;       // 8B half within chunk

    auto convert_write = [&](int sl, int buf) {
#pragma unroll
        for (int j = 0; j < 4; ++j) {
            f32x4 u = a_reg[sl][j];
            i32x2 d;
            d[0] = pk(u[0], u[1]);
            d[1] = pk(u[2], u[3]);
            int row = j * 16 + g;
            int pos = a_chunk ^ (row & 7);
            *(i32x2*)&As[buf][row * BK + pos * 8 + a_half * 4] = d;
        }
#pragma unroll
        for (int j = 0; j < 4; ++j) {
            f32x4 u = w_reg[sl][j];
            i32x2 d;
            d[0] = pk(u[0], u[1]);
            d[1] = pk(u[2], u[3]);
            int row = j * 16 + g;
            int pos = a_chunk ^ (row & 7);
            *(i32x2*)&Bs[buf][row * BK + pos * 8 + a_half * 4] = d;
        }
        if (do_bounds) {
            f32x4 l = lo_reg[sl], h = hi_reg[sl];
#pragma unroll
            for (int j = 0; j < 4; ++j) {
                f32x4 w = w_reg[sl][j];
#pragma unroll
                for (int e = 0; e < 4; ++e) {
                    float wv = w[e];
                    P[j] = fmaf(wv,        l[e] + h[e], P[j]);
                    R[j] = fmaf(fabsf(wv), h[e] - l[e], R[j]);
                }
            }
        }
    };

    auto mfma_tile = [&](int buf) {
#pragma unroll
        for (int s = 0; s < 2; ++s) {
            s16x8 af[2], bf[2];
#pragma unroll
            for (int mi = 0; mi < 2; ++mi) {
                int row = wm * 32 + mi * 16 + l15;
                int pos = (s * 4 + lq) ^ (row & 7);
                af[mi] = *(const s16x8*)&As[buf][row * BK + pos * 8];
            }
#pragma unroll
            for (int ni = 0; ni < 2; ++ni) {
                int row = wn * 32 + ni * 16 + l15;
                int pos = (s * 4 + lq) ^ (row & 7);
                bf[ni] = *(const s16x8*)&Bs[buf][row * BK + pos * 8];
            }
#pragma unroll
            for (int mi = 0; mi < 2; ++mi)
#pragma unroll
                for (int ni = 0; ni < 2; ++ni)
                    acc[mi][ni] = __builtin_amdgcn_mfma_f32_16x16x32_bf16(
                        af[mi], bf[ni], acc[mi][ni], 0, 0, 0);
        }
    };

    // ---- prologue: tiles 0,1 in flight; tile 0 staged to LDS buf 0 ----
    issue(0, 0);
    issue(1, 1);
    convert_write(0, 0);
    barrier_lds();

    // ---- main pipeline, unrolled x2 (slot/buf indices literal) ----
    for (int it = 0; it < KITERS - 2; it += 2) {
        issue(0, it + 2);
        mfma_tile(0);
        convert_write(1, 1);
        barrier_lds();

        issue(1, it + 3);
        mfma_tile(1);
        convert_write(0, 0);
        barrier_lds();
    }
    // tail: tiles 126, 127
    mfma_tile(0);
    convert_write(1, 1);
    barrier_lds();
    mfma_tile(1);

    // ---- epilogue: y = acc + b  (C/D layout: col = lane&15, row = lq*4+reg) ----
#pragma unroll
    for (int ni = 0; ni < 2; ++ni) {
        int go = n0 + wn * 32 + ni * 16 + l15;
        float bv = bias[go];
#pragma unroll
        for (int mi = 0; mi < 2; ++mi) {
            int gr = m0 + wm * 32 + mi * 16 + lq * 4;
#pragma unroll
            for (int r = 0; r < 4; ++r)
                out[(size_t)(gr + r) * N_TOTAL + go] = acc[mi][ni][r] + bv;
        }
    }

    // ---- epilogue: bounds (reduce over the 16 lanes sharing t>>4) ----
    if (do_bounds) {
#pragma unroll
        for (int j = 0; j < 4; ++j) {
            float p = P[j], r = R[j];
            p += __shfl_xor(p, 1);
            p += __shfl_xor(p, 2);
            p += __shfl_xor(p, 4);
            p += __shfl_xor(p, 8);
            r += __shfl_xor(r, 1);
            r += __shfl_xor(r, 2);
            r += __shfl_xor(r, 4);
            r += __shfl_xor(r, 8);
            if (sg == 0) {
                int o = n0 + j * 16 + g;
                float bv = bias[o];
                out[(size_t)M_TOTAL * N_TOTAL + o]           = 0.5f * (p - r) + bv;
                out[(size_t)M_TOTAL * N_TOTAL + N_TOTAL + o] = 0.5f * (p + r) + bv;
            }
        }
    }
}

extern "C" void kernel_launch(void* const* d_in, const int* in_sizes, int n_in,
                              void* d_out, int out_size, void* d_ws, size_t ws_size,
                              hipStream_t stream) {
    const float* x    = (const float*)d_in[0];
    const float* low  = (const float*)d_in[1];
    const float* high = (const float*)d_in[2];
    const float* W    = (const float*)d_in[3];
    const float* b    = (const float*)d_in[4];
    float* out = (float*)d_out;

    dim3 grid(4 * (N_TOTAL / TN));   // 512 blocks: 4 M-tiles x 128 N-tiles
    dim3 block(256);
    hipLaunchKernelGGL(abstract_linear_kernel, grid, block, 0, stream,
                       x, low, high, W, b, out);
}